// Round 1
// baseline (34.460 us; speedup 1.0000x reference)
//
#include <hip/hip_runtime.h>

#define GRIDN 256
#define SX (GRIDN * GRIDN)   // x-stride in elements (65536)
#define SY (GRIDN)           // y-stride (256)

// ---------------------------------------------------------------------------
// Tiny prelude: general 4x4 inverse (adjugate) of the affine, computed once
// into workspace. Matches jnp.linalg.inv for any invertible affine.
// ---------------------------------------------------------------------------
__global__ void invert4_kernel(const float* __restrict__ A, float* __restrict__ out) {
    if (threadIdx.x != 0 || blockIdx.x != 0) return;
    float m[16];
#pragma unroll
    for (int i = 0; i < 16; ++i) m[i] = A[i];
    float inv[16];
    inv[0]  =  m[5]*m[10]*m[15] - m[5]*m[11]*m[14] - m[9]*m[6]*m[15] + m[9]*m[7]*m[14] + m[13]*m[6]*m[11] - m[13]*m[7]*m[10];
    inv[4]  = -m[4]*m[10]*m[15] + m[4]*m[11]*m[14] + m[8]*m[6]*m[15] - m[8]*m[7]*m[14] - m[12]*m[6]*m[11] + m[12]*m[7]*m[10];
    inv[8]  =  m[4]*m[9]*m[15]  - m[4]*m[11]*m[13] - m[8]*m[5]*m[15] + m[8]*m[7]*m[13] + m[12]*m[5]*m[11] - m[12]*m[7]*m[9];
    inv[12] = -m[4]*m[9]*m[14]  + m[4]*m[10]*m[13] + m[8]*m[5]*m[14] - m[8]*m[6]*m[13] - m[12]*m[5]*m[10] + m[12]*m[6]*m[9];
    inv[1]  = -m[1]*m[10]*m[15] + m[1]*m[11]*m[14] + m[9]*m[2]*m[15] - m[9]*m[3]*m[14] - m[13]*m[2]*m[11] + m[13]*m[3]*m[10];
    inv[5]  =  m[0]*m[10]*m[15] - m[0]*m[11]*m[14] - m[8]*m[2]*m[15] + m[8]*m[3]*m[14] + m[12]*m[2]*m[11] - m[12]*m[3]*m[10];
    inv[9]  = -m[0]*m[9]*m[15]  + m[0]*m[11]*m[13] + m[8]*m[1]*m[15] - m[8]*m[3]*m[13] - m[12]*m[1]*m[11] + m[12]*m[3]*m[9];
    inv[13] =  m[0]*m[9]*m[14]  - m[0]*m[10]*m[13] - m[8]*m[1]*m[14] + m[8]*m[2]*m[13] + m[12]*m[1]*m[10] - m[12]*m[2]*m[9];
    inv[2]  =  m[1]*m[6]*m[15]  - m[1]*m[7]*m[14]  - m[5]*m[2]*m[15] + m[5]*m[3]*m[14] + m[13]*m[2]*m[7]  - m[13]*m[3]*m[6];
    inv[6]  = -m[0]*m[6]*m[15]  + m[0]*m[7]*m[14]  + m[4]*m[2]*m[15] - m[4]*m[3]*m[14] - m[12]*m[2]*m[7]  + m[12]*m[3]*m[6];
    inv[10] =  m[0]*m[5]*m[15]  - m[0]*m[7]*m[13]  - m[4]*m[1]*m[15] + m[4]*m[3]*m[13] + m[12]*m[1]*m[7]  - m[12]*m[3]*m[5];
    inv[14] = -m[0]*m[5]*m[14]  + m[0]*m[6]*m[13]  + m[4]*m[1]*m[14] - m[4]*m[2]*m[13] - m[12]*m[1]*m[6]  + m[12]*m[2]*m[5];
    inv[3]  = -m[1]*m[6]*m[11]  + m[1]*m[7]*m[10]  + m[5]*m[2]*m[11] - m[5]*m[3]*m[10] - m[9]*m[2]*m[7]   + m[9]*m[3]*m[6];
    inv[7]  =  m[0]*m[6]*m[11]  - m[0]*m[7]*m[10]  - m[4]*m[2]*m[11] + m[4]*m[3]*m[10] + m[8]*m[2]*m[7]   - m[8]*m[3]*m[6];
    inv[11] = -m[0]*m[5]*m[11]  + m[0]*m[7]*m[9]   + m[4]*m[1]*m[11] - m[4]*m[3]*m[9]  - m[8]*m[1]*m[7]   + m[8]*m[3]*m[5];
    inv[15] =  m[0]*m[5]*m[10]  - m[0]*m[6]*m[9]   - m[4]*m[1]*m[10] + m[4]*m[2]*m[9]  + m[8]*m[1]*m[6]   - m[8]*m[2]*m[5];
    float det = m[0]*inv[0] + m[1]*inv[4] + m[2]*inv[8] + m[3]*inv[12];
    float r = 1.0f / det;
#pragma unroll
    for (int i = 0; i < 16; ++i) out[i] = inv[i] * r;
}

// ---------------------------------------------------------------------------
// Main kernel: one thread per particle.
// out row (12 f32): [drift.x, drift.y, drift.z, L00, 0, 0, L10, L11, 0, L20, L21, L22]
// ---------------------------------------------------------------------------
__global__ __launch_bounds__(256) void sde_kernel(
    const float* __restrict__ pot,    // (256,256,256)
    const float* __restrict__ vec,    // (256,256,256,3)
    const float* __restrict__ ainv,   // 16 floats (4x4 inverse of affine)
    const float* __restrict__ pos,    // (N,3)
    float* __restrict__ out,          // (N,12)
    int n)
{
    int p = blockIdx.x * 256 + threadIdx.x;
    if (p >= n) return;

    float px = pos[3 * p + 0];
    float py = pos[3 * p + 1];
    float pz = pos[3 * p + 2];

    // rows 0..2 of Ainv: vox_j = M[j][0]*px + M[j][1]*py + M[j][2]*pz + M[j][3]
    float M00 = ainv[0],  M01 = ainv[1],  M02 = ainv[2],  T0 = ainv[3];
    float M10 = ainv[4],  M11 = ainv[5],  M12 = ainv[6],  T1 = ainv[7];
    float M20 = ainv[8],  M21 = ainv[9],  M22 = ainv[10], T2 = ainv[11];

    float vxp = M00 * px + M01 * py + M02 * pz + T0;
    float vyp = M10 * px + M11 * py + M12 * pz + T1;
    float vzp = M20 * px + M21 * py + M22 * pz + T2;

    int ix = min(max((int)floorf(vxp), 0), GRIDN - 2);
    int iy = min(max((int)floorf(vyp), 0), GRIDN - 2);
    int iz = min(max((int)floorf(vzp), 0), GRIDN - 2);
    float fx = vxp - (float)ix;
    float fy = vyp - (float)iy;
    float fz = vzp - (float)iz;
    float gx = 1.0f - fx, gy = 1.0f - fy, gz = 1.0f - fz;

    int base = ix * SX + iy * SY + iz;

    // ---- potential gather (8 corners) ----
    const float* P0 = pot + base;
    float c000 = P0[0],        c001 = P0[1];
    float c010 = P0[SY],       c011 = P0[SY + 1];
    float c100 = P0[SX],       c101 = P0[SX + 1];
    float c110 = P0[SX + SY],  c111 = P0[SX + SY + 1];

    // analytic trilinear gradient wrt (fx,fy,fz)
    float wyz00 = gy * gz, wyz01 = gy * fz, wyz10 = fy * gz, wyz11 = fy * fz;
    float dUdfx = (c100 - c000) * wyz00 + (c110 - c010) * wyz10
                + (c101 - c001) * wyz01 + (c111 - c011) * wyz11;
    float dUdfy = ((c010 - c000) * gz + (c011 - c001) * fz) * gx
                + ((c110 - c100) * gz + (c111 - c101) * fz) * fx;
    float dUdfz = ((c001 - c000) * gy + (c011 - c010) * fy) * gx
                + ((c101 - c100) * gy + (c111 - c110) * fy) * fx;

    // chain rule through vox = p @ M^T + t:  dU/dp_k = sum_j dU/dvox_j * M[j][k]
    float gpx = dUdfx * M00 + dUdfy * M10 + dUdfz * M20;
    float gpy = dUdfx * M01 + dUdfy * M11 + dUdfz * M21;
    float gpz = dUdfx * M02 + dUdfy * M12 + dUdfz * M22;

    const float K_CONF = 10.0f;
    float dr0 = -K_CONF * gpx;
    float dr1 = -K_CONF * gpy;
    float dr2 = -K_CONF * gpz;

    // ---- vector field gather (8 corners x 3 channels) ----
    float w000 = gx * wyz00, w001 = gx * wyz01, w010 = gx * wyz10, w011 = gx * wyz11;
    float w100 = fx * wyz00, w101 = fx * wyz01, w110 = fx * wyz10, w111 = fx * wyz11;

    const float* V = vec + (size_t)base * 3;
    const int VY = SY * 3;       // 768
    const int VX = SX * 3;       // 196608

    float v0 = 0.f, v1 = 0.f, v2 = 0.f;
    {
        const float* c = V;            // (0,0,0) and (0,0,1)
        v0 += w000 * c[0] + w001 * c[3];
        v1 += w000 * c[1] + w001 * c[4];
        v2 += w000 * c[2] + w001 * c[5];
    }
    {
        const float* c = V + VY;       // (0,1,0) and (0,1,1)
        v0 += w010 * c[0] + w011 * c[3];
        v1 += w010 * c[1] + w011 * c[4];
        v2 += w010 * c[2] + w011 * c[5];
    }
    {
        const float* c = V + VX;       // (1,0,0) and (1,0,1)
        v0 += w100 * c[0] + w101 * c[3];
        v1 += w100 * c[1] + w101 * c[4];
        v2 += w100 * c[2] + w101 * c[5];
    }
    {
        const float* c = V + VX + VY;  // (1,1,0) and (1,1,1)
        v0 += w110 * c[0] + w111 * c[3];
        v1 += w110 * c[1] + w111 * c[4];
        v2 += w110 * c[2] + w111 * c[5];
    }

    // ---- normalize + diffusion tensor + 3x3 Cholesky ----
    const float EPS_NORM = 1e-9f;
    const float EPS_CHOL = 1e-6f;
    const float D_LONG = 0.0017f, D_TRANS = 0.0002f;

    float nv = sqrtf(v0 * v0 + v1 * v1 + v2 * v2) + EPS_NORM;
    float ux = v0 / nv, uy = v1 / nv, uz = v2 / nv;

    float d00 = D_LONG * ux * ux + D_TRANS * (1.0f - ux * ux) + EPS_CHOL;
    float d11 = D_LONG * uy * uy + D_TRANS * (1.0f - uy * uy) + EPS_CHOL;
    float d22 = D_LONG * uz * uz + D_TRANS * (1.0f - uz * uz) + EPS_CHOL;
    float d10 = D_LONG * uy * ux + D_TRANS * (0.0f - uy * ux);
    float d20 = D_LONG * uz * ux + D_TRANS * (0.0f - uz * ux);
    float d21 = D_LONG * uz * uy + D_TRANS * (0.0f - uz * uy);

    float L00 = sqrtf(d00);
    float L10 = d10 / L00;
    float L20 = d20 / L00;
    float L11 = sqrtf(d11 - L10 * L10);
    float L21 = (d21 - L20 * L10) / L11;
    float L22 = sqrtf(d22 - L20 * L20 - L21 * L21);

    // ---- write 12 floats as 3x float4 (48B stride, 16B aligned) ----
    float4* o = (float4*)(out + (size_t)p * 12);
    o[0] = make_float4(dr0, dr1, dr2, L00);
    o[1] = make_float4(0.0f, 0.0f, L10, L11);
    o[2] = make_float4(0.0f, L20, L21, L22);
}

extern "C" void kernel_launch(void* const* d_in, const int* in_sizes, int n_in,
                              void* d_out, int out_size, void* d_ws, size_t ws_size,
                              hipStream_t stream) {
    const float* pot = (const float*)d_in[0];   // potential_field (256^3)
    const float* vec = (const float*)d_in[1];   // vector_field (256^3 x 3)
    const float* aff = (const float*)d_in[2];   // affine 4x4
    const float* pos = (const float*)d_in[3];   // positions (N,3)
    float* out = (float*)d_out;
    float* ainv = (float*)d_ws;                 // 16 floats scratch

    int n = in_sizes[3] / 3;

    invert4_kernel<<<1, 64, 0, stream>>>(aff, ainv);
    sde_kernel<<<(n + 255) / 256, 256, 0, stream>>>(pot, vec, ainv, pos, out, n);
}

// Round 2
// 29.279 us; speedup vs baseline: 1.1769x; 1.1769x over previous
//
#include <hip/hip_runtime.h>

#define GRIDN 256
#define SX (GRIDN * GRIDN)   // x-stride in elements (65536)
#define SY (GRIDN)           // y-stride (256)

// ---------------------------------------------------------------------------
// Single fused kernel: one thread per particle. Each thread redundantly
// computes the 4x4 affine inverse from 16 wave-uniform (s_load'd, L2-cached)
// floats — ~100 VALU ops, hidden under gather latency. This removes the
// serial invert4 graph node (~3-5us launch + dependency stall).
// out row (12 f32): [drift.x, drift.y, drift.z, L00, 0, 0, L10, L11, 0, L20, L21, L22]
// ---------------------------------------------------------------------------
__global__ __launch_bounds__(256) void sde_kernel(
    const float* __restrict__ pot,    // (256,256,256)
    const float* __restrict__ vec,    // (256,256,256,3)
    const float* __restrict__ aff,    // 4x4 affine (row-major)
    const float* __restrict__ pos,    // (N,3)
    float* __restrict__ out,          // (N,12)
    int n)
{
    int p = blockIdx.x * 256 + threadIdx.x;
    if (p >= n) return;

    // ---- issue position loads early ----
    float px = pos[3 * p + 0];
    float py = pos[3 * p + 1];
    float pz = pos[3 * p + 2];

    // ---- per-thread 4x4 adjugate inverse of the (uniform) affine ----
    float m[16];
#pragma unroll
    for (int i = 0; i < 16; ++i) m[i] = aff[i];

    float i0, i4, i8, i12, i1, i5, i9, i2, i6, i10;
    i0  =  m[5]*m[10]*m[15] - m[5]*m[11]*m[14] - m[9]*m[6]*m[15] + m[9]*m[7]*m[14] + m[13]*m[6]*m[11] - m[13]*m[7]*m[10];
    i4  = -m[4]*m[10]*m[15] + m[4]*m[11]*m[14] + m[8]*m[6]*m[15] - m[8]*m[7]*m[14] - m[12]*m[6]*m[11] + m[12]*m[7]*m[10];
    i8  =  m[4]*m[9]*m[15]  - m[4]*m[11]*m[13] - m[8]*m[5]*m[15] + m[8]*m[7]*m[13] + m[12]*m[5]*m[11] - m[12]*m[7]*m[9];
    i12 = -m[4]*m[9]*m[14]  + m[4]*m[10]*m[13] + m[8]*m[5]*m[14] - m[8]*m[6]*m[13] - m[12]*m[5]*m[10] + m[12]*m[6]*m[9];
    i1  = -m[1]*m[10]*m[15] + m[1]*m[11]*m[14] + m[9]*m[2]*m[15] - m[9]*m[3]*m[14] - m[13]*m[2]*m[11] + m[13]*m[3]*m[10];
    i5  =  m[0]*m[10]*m[15] - m[0]*m[11]*m[14] - m[8]*m[2]*m[15] + m[8]*m[3]*m[14] + m[12]*m[2]*m[11] - m[12]*m[3]*m[10];
    i9  = -m[0]*m[9]*m[15]  + m[0]*m[11]*m[13] + m[8]*m[1]*m[15] - m[8]*m[3]*m[13] - m[12]*m[1]*m[11] + m[12]*m[3]*m[9];
    i2  =  m[1]*m[6]*m[15]  - m[1]*m[7]*m[14]  - m[5]*m[2]*m[15] + m[5]*m[3]*m[14] + m[13]*m[2]*m[7]  - m[13]*m[3]*m[6];
    i6  = -m[0]*m[6]*m[15]  + m[0]*m[7]*m[14]  + m[4]*m[2]*m[15] - m[4]*m[3]*m[14] - m[12]*m[2]*m[7]  + m[12]*m[3]*m[6];
    i10 =  m[0]*m[5]*m[15]  - m[0]*m[7]*m[13]  - m[4]*m[1]*m[15] + m[4]*m[3]*m[13] + m[12]*m[1]*m[7]  - m[12]*m[3]*m[5];
    // only need rows 0..2 of the inverse (cols of adjugate^T): i3/i7/i11 row
    float i3, i7, i11;
    i3  = -m[1]*m[6]*m[11]  + m[1]*m[7]*m[10]  + m[5]*m[2]*m[11] - m[5]*m[3]*m[10] - m[9]*m[2]*m[7]   + m[9]*m[3]*m[6];
    i7  =  m[0]*m[6]*m[11]  - m[0]*m[7]*m[10]  - m[4]*m[2]*m[11] + m[4]*m[3]*m[10] + m[8]*m[2]*m[7]   - m[8]*m[3]*m[6];
    i11 = -m[0]*m[5]*m[11]  + m[0]*m[7]*m[9]   + m[4]*m[1]*m[11] - m[4]*m[3]*m[9]  - m[8]*m[1]*m[7]   + m[8]*m[3]*m[5];

    float det = m[0]*i0 + m[1]*i4 + m[2]*i8 + m[3]*i12;
    float r = 1.0f / det;

    // Ainv row-major entries we use: M[j][k] = inv[4j+k], T[j] = inv[4j+3]
    float M00 = i0 * r,  M01 = i1 * r,  M02 = i2 * r,  T0 = i3 * r;
    float M10 = i4 * r,  M11 = i5 * r,  M12 = i6 * r,  T1 = i7 * r;
    float M20 = i8 * r,  M21 = i9 * r,  M22 = i10 * r, T2 = i11 * r;

    float vxp = M00 * px + M01 * py + M02 * pz + T0;
    float vyp = M10 * px + M11 * py + M12 * pz + T1;
    float vzp = M20 * px + M21 * py + M22 * pz + T2;

    int ix = min(max((int)floorf(vxp), 0), GRIDN - 2);
    int iy = min(max((int)floorf(vyp), 0), GRIDN - 2);
    int iz = min(max((int)floorf(vzp), 0), GRIDN - 2);
    float fx = vxp - (float)ix;
    float fy = vyp - (float)iy;
    float fz = vzp - (float)iz;
    float gx = 1.0f - fx, gy = 1.0f - fy, gz = 1.0f - fz;

    int base = ix * SX + iy * SY + iz;

    // ---- potential gather (8 corners) ----
    const float* P0 = pot + base;
    float c000 = P0[0],        c001 = P0[1];
    float c010 = P0[SY],       c011 = P0[SY + 1];
    float c100 = P0[SX],       c101 = P0[SX + 1];
    float c110 = P0[SX + SY],  c111 = P0[SX + SY + 1];

    // ---- vector field gather (8 corners x 3 channels) — issue before use ----
    const float* V = vec + (size_t)base * 3;
    const int VY = SY * 3;       // 768
    const int VX = SX * 3;       // 196608
    float a0 = V[0],        a1 = V[1],        a2 = V[2],        a3 = V[3],        a4 = V[4],        a5 = V[5];
    const float* Vb = V + VY;
    float b0 = Vb[0], b1 = Vb[1], b2 = Vb[2], b3 = Vb[3], b4 = Vb[4], b5 = Vb[5];
    const float* Vc = V + VX;
    float e0 = Vc[0], e1 = Vc[1], e2 = Vc[2], e3 = Vc[3], e4 = Vc[4], e5 = Vc[5];
    const float* Vd = V + VX + VY;
    float d0 = Vd[0], d1 = Vd[1], d2 = Vd[2], d3 = Vd[3], d4 = Vd[4], d5 = Vd[5];

    // analytic trilinear gradient wrt (fx,fy,fz)
    float wyz00 = gy * gz, wyz01 = gy * fz, wyz10 = fy * gz, wyz11 = fy * fz;
    float dUdfx = (c100 - c000) * wyz00 + (c110 - c010) * wyz10
                + (c101 - c001) * wyz01 + (c111 - c011) * wyz11;
    float dUdfy = ((c010 - c000) * gz + (c011 - c001) * fz) * gx
                + ((c110 - c100) * gz + (c111 - c101) * fz) * fx;
    float dUdfz = ((c001 - c000) * gy + (c011 - c010) * fy) * gx
                + ((c101 - c100) * gy + (c111 - c110) * fy) * fx;

    // chain rule through vox = p @ M^T + t
    float gpx = dUdfx * M00 + dUdfy * M10 + dUdfz * M20;
    float gpy = dUdfx * M01 + dUdfy * M11 + dUdfz * M21;
    float gpz = dUdfx * M02 + dUdfy * M12 + dUdfz * M22;

    const float K_CONF = 10.0f;
    float dr0 = -K_CONF * gpx;
    float dr1 = -K_CONF * gpy;
    float dr2 = -K_CONF * gpz;

    // ---- trilinear blend of vector field ----
    float w000 = gx * wyz00, w001 = gx * wyz01, w010 = gx * wyz10, w011 = gx * wyz11;
    float w100 = fx * wyz00, w101 = fx * wyz01, w110 = fx * wyz10, w111 = fx * wyz11;

    float v0 = w000 * a0 + w001 * a3 + w010 * b0 + w011 * b3
             + w100 * e0 + w101 * e3 + w110 * d0 + w111 * d3;
    float v1 = w000 * a1 + w001 * a4 + w010 * b1 + w011 * b4
             + w100 * e1 + w101 * e4 + w110 * d1 + w111 * d4;
    float v2 = w000 * a2 + w001 * a5 + w010 * b2 + w011 * b5
             + w100 * e2 + w101 * e5 + w110 * d2 + w111 * d5;

    // ---- normalize + diffusion tensor + 3x3 Cholesky ----
    const float EPS_NORM = 1e-9f;
    const float EPS_CHOL = 1e-6f;
    const float D_LONG = 0.0017f, D_TRANS = 0.0002f;

    float nv = sqrtf(v0 * v0 + v1 * v1 + v2 * v2) + EPS_NORM;
    float ux = v0 / nv, uy = v1 / nv, uz = v2 / nv;

    float d00 = D_LONG * ux * ux + D_TRANS * (1.0f - ux * ux) + EPS_CHOL;
    float d11 = D_LONG * uy * uy + D_TRANS * (1.0f - uy * uy) + EPS_CHOL;
    float d22 = D_LONG * uz * uz + D_TRANS * (1.0f - uz * uz) + EPS_CHOL;
    float d10 = (D_LONG - D_TRANS) * uy * ux;
    float d20 = (D_LONG - D_TRANS) * uz * ux;
    float d21 = (D_LONG - D_TRANS) * uz * uy;

    float L00 = sqrtf(d00);
    float L10 = d10 / L00;
    float L20 = d20 / L00;
    float L11 = sqrtf(d11 - L10 * L10);
    float L21 = (d21 - L20 * L10) / L11;
    float L22 = sqrtf(d22 - L20 * L20 - L21 * L21);

    // ---- write 12 floats as 3x float4 (48B stride, 16B aligned) ----
    float4* o = (float4*)(out + (size_t)p * 12);
    o[0] = make_float4(dr0, dr1, dr2, L00);
    o[1] = make_float4(0.0f, 0.0f, L10, L11);
    o[2] = make_float4(0.0f, L20, L21, L22);
}

extern "C" void kernel_launch(void* const* d_in, const int* in_sizes, int n_in,
                              void* d_out, int out_size, void* d_ws, size_t ws_size,
                              hipStream_t stream) {
    const float* pot = (const float*)d_in[0];   // potential_field (256^3)
    const float* vec = (const float*)d_in[1];   // vector_field (256^3 x 3)
    const float* aff = (const float*)d_in[2];   // affine 4x4
    const float* pos = (const float*)d_in[3];   // positions (N,3)
    float* out = (float*)d_out;

    int n = in_sizes[3] / 3;

    sde_kernel<<<(n + 255) / 256, 256, 0, stream>>>(pot, vec, aff, pos, out, n);
}

// Round 3
// 29.249 us; speedup vs baseline: 1.1781x; 1.0010x over previous
//
#include <hip/hip_runtime.h>

#define GRIDN 256
#define SX (GRIDN * GRIDN)   // x-stride in elements (65536)
#define SY (GRIDN)           // y-stride (256)

// ---------------------------------------------------------------------------
// One thread per particle, single fused kernel.
// Gathers use wide (x2/x4) loads at 4B-actual alignment: gfx950 HW supports
// unaligned global access; this halves gather request count vs scalar dwords
// (36 -> ~17 line-requests per thread), attacking the request-throughput bound.
// out row (12 f32): [drift.x,y,z, L00, 0, 0, L10, L11, 0, L20, L21, L22]
// ---------------------------------------------------------------------------
__global__ __launch_bounds__(256) void sde_kernel(
    const float* __restrict__ pot,    // (256,256,256)
    const float* __restrict__ vec,    // (256,256,256,3)
    const float* __restrict__ aff,    // 4x4 affine (row-major)
    const float* __restrict__ pos,    // (N,3)
    float* __restrict__ out,          // (N,12)
    int n)
{
    int p = blockIdx.x * 256 + threadIdx.x;
    if (p >= n) return;

    // ---- position load: float2 + float (2 requests, coalesced) ----
    float2 p01 = *reinterpret_cast<const float2*>(pos + 3 * (size_t)p);
    float  p2  = pos[3 * (size_t)p + 2];
    float px = p01.x, py = p01.y, pz = p2;

    // ---- per-thread 4x4 adjugate inverse of the (uniform) affine ----
    float m[16];
#pragma unroll
    for (int i = 0; i < 16; ++i) m[i] = aff[i];

    float i0, i4, i8, i12, i1, i5, i9, i2, i6, i10, i3, i7, i11;
    i0  =  m[5]*m[10]*m[15] - m[5]*m[11]*m[14] - m[9]*m[6]*m[15] + m[9]*m[7]*m[14] + m[13]*m[6]*m[11] - m[13]*m[7]*m[10];
    i4  = -m[4]*m[10]*m[15] + m[4]*m[11]*m[14] + m[8]*m[6]*m[15] - m[8]*m[7]*m[14] - m[12]*m[6]*m[11] + m[12]*m[7]*m[10];
    i8  =  m[4]*m[9]*m[15]  - m[4]*m[11]*m[13] - m[8]*m[5]*m[15] + m[8]*m[7]*m[13] + m[12]*m[5]*m[11] - m[12]*m[7]*m[9];
    i12 = -m[4]*m[9]*m[14]  + m[4]*m[10]*m[13] + m[8]*m[5]*m[14] - m[8]*m[6]*m[13] - m[12]*m[5]*m[10] + m[12]*m[6]*m[9];
    i1  = -m[1]*m[10]*m[15] + m[1]*m[11]*m[14] + m[9]*m[2]*m[15] - m[9]*m[3]*m[14] - m[13]*m[2]*m[11] + m[13]*m[3]*m[10];
    i5  =  m[0]*m[10]*m[15] - m[0]*m[11]*m[14] - m[8]*m[2]*m[15] + m[8]*m[3]*m[14] + m[12]*m[2]*m[11] - m[12]*m[3]*m[10];
    i9  = -m[0]*m[9]*m[15]  + m[0]*m[11]*m[13] + m[8]*m[1]*m[15] - m[8]*m[3]*m[13] - m[12]*m[1]*m[11] + m[12]*m[3]*m[9];
    i2  =  m[1]*m[6]*m[15]  - m[1]*m[7]*m[14]  - m[5]*m[2]*m[15] + m[5]*m[3]*m[14] + m[13]*m[2]*m[7]  - m[13]*m[3]*m[6];
    i6  = -m[0]*m[6]*m[15]  + m[0]*m[7]*m[14]  + m[4]*m[2]*m[15] - m[4]*m[3]*m[14] - m[12]*m[2]*m[7]  + m[12]*m[3]*m[6];
    i10 =  m[0]*m[5]*m[15]  - m[0]*m[7]*m[13]  - m[4]*m[1]*m[15] + m[4]*m[3]*m[13] + m[12]*m[1]*m[7]  - m[12]*m[3]*m[5];
    i3  = -m[1]*m[6]*m[11]  + m[1]*m[7]*m[10]  + m[5]*m[2]*m[11] - m[5]*m[3]*m[10] - m[9]*m[2]*m[7]   + m[9]*m[3]*m[6];
    i7  =  m[0]*m[6]*m[11]  - m[0]*m[7]*m[10]  - m[4]*m[2]*m[11] + m[4]*m[3]*m[10] + m[8]*m[2]*m[7]   - m[8]*m[3]*m[6];
    i11 = -m[0]*m[5]*m[11]  + m[0]*m[7]*m[9]   + m[4]*m[1]*m[11] - m[4]*m[3]*m[9]  - m[8]*m[1]*m[7]   + m[8]*m[3]*m[5];

    float det = m[0]*i0 + m[1]*i4 + m[2]*i8 + m[3]*i12;
    float r = 1.0f / det;

    float M00 = i0 * r,  M01 = i1 * r,  M02 = i2 * r,  T0 = i3 * r;
    float M10 = i4 * r,  M11 = i5 * r,  M12 = i6 * r,  T1 = i7 * r;
    float M20 = i8 * r,  M21 = i9 * r,  M22 = i10 * r, T2 = i11 * r;

    float vxp = M00 * px + M01 * py + M02 * pz + T0;
    float vyp = M10 * px + M11 * py + M12 * pz + T1;
    float vzp = M20 * px + M21 * py + M22 * pz + T2;

    int ix = min(max((int)floorf(vxp), 0), GRIDN - 2);
    int iy = min(max((int)floorf(vyp), 0), GRIDN - 2);
    int iz = min(max((int)floorf(vzp), 0), GRIDN - 2);
    float fx = vxp - (float)ix;
    float fy = vyp - (float)iy;
    float fz = vzp - (float)iz;
    float gx = 1.0f - fx, gy = 1.0f - fy, gz = 1.0f - fz;

    int base = ix * SX + iy * SY + iz;

    // ---- potential gather: 4 z-pairs as float2 (1 request each) ----
    const float* P0 = pot + base;
    float2 zA = *reinterpret_cast<const float2*>(P0);            // c000,c001
    float2 zB = *reinterpret_cast<const float2*>(P0 + SY);       // c010,c011
    float2 zC = *reinterpret_cast<const float2*>(P0 + SX);       // c100,c101
    float2 zD = *reinterpret_cast<const float2*>(P0 + SX + SY);  // c110,c111

    // ---- vector field gather: 4 segments of 24B as float4+float2 ----
    const float* V = vec + (size_t)base * 3;
    const int VY = SY * 3;       // 768
    const int VX = SX * 3;       // 196608

    float4 qa = *reinterpret_cast<const float4*>(V);
    float2 ra = *reinterpret_cast<const float2*>(V + 4);
    float4 qb = *reinterpret_cast<const float4*>(V + VY);
    float2 rb = *reinterpret_cast<const float2*>(V + VY + 4);
    float4 qc = *reinterpret_cast<const float4*>(V + VX);
    float2 rc = *reinterpret_cast<const float2*>(V + VX + 4);
    float4 qd = *reinterpret_cast<const float4*>(V + VX + VY);
    float2 rd = *reinterpret_cast<const float2*>(V + VX + VY + 4);

    float c000 = zA.x, c001 = zA.y;
    float c010 = zB.x, c011 = zB.y;
    float c100 = zC.x, c101 = zC.y;
    float c110 = zD.x, c111 = zD.y;

    // analytic trilinear gradient wrt (fx,fy,fz)
    float wyz00 = gy * gz, wyz01 = gy * fz, wyz10 = fy * gz, wyz11 = fy * fz;
    float dUdfx = (c100 - c000) * wyz00 + (c110 - c010) * wyz10
                + (c101 - c001) * wyz01 + (c111 - c011) * wyz11;
    float dUdfy = ((c010 - c000) * gz + (c011 - c001) * fz) * gx
                + ((c110 - c100) * gz + (c111 - c101) * fz) * fx;
    float dUdfz = ((c001 - c000) * gy + (c011 - c010) * fy) * gx
                + ((c101 - c100) * gy + (c111 - c110) * fy) * fx;

    // chain rule through vox = p @ M^T + t
    float gpx = dUdfx * M00 + dUdfy * M10 + dUdfz * M20;
    float gpy = dUdfx * M01 + dUdfy * M11 + dUdfz * M21;
    float gpz = dUdfx * M02 + dUdfy * M12 + dUdfz * M22;

    const float K_CONF = 10.0f;
    float dr0 = -K_CONF * gpx;
    float dr1 = -K_CONF * gpy;
    float dr2 = -K_CONF * gpz;

    // ---- trilinear blend of vector field ----
    float w000 = gx * wyz00, w001 = gx * wyz01, w010 = gx * wyz10, w011 = gx * wyz11;
    float w100 = fx * wyz00, w101 = fx * wyz01, w110 = fx * wyz10, w111 = fx * wyz11;

    float v0 = w000 * qa.x + w001 * qa.w + w010 * qb.x + w011 * qb.w
             + w100 * qc.x + w101 * qc.w + w110 * qd.x + w111 * qd.w;
    float v1 = w000 * qa.y + w001 * ra.x + w010 * qb.y + w011 * rb.x
             + w100 * qc.y + w101 * rc.x + w110 * qd.y + w111 * rd.x;
    float v2 = w000 * qa.z + w001 * ra.y + w010 * qb.z + w011 * rb.y
             + w100 * qc.z + w101 * rc.y + w110 * qd.z + w111 * rd.y;

    // ---- normalize + diffusion tensor + 3x3 Cholesky ----
    const float EPS_NORM = 1e-9f;
    const float EPS_CHOL = 1e-6f;
    const float D_LONG = 0.0017f, D_TRANS = 0.0002f;

    float nv = sqrtf(v0 * v0 + v1 * v1 + v2 * v2) + EPS_NORM;
    float ux = v0 / nv, uy = v1 / nv, uz = v2 / nv;

    float d00 = D_LONG * ux * ux + D_TRANS * (1.0f - ux * ux) + EPS_CHOL;
    float d11 = D_LONG * uy * uy + D_TRANS * (1.0f - uy * uy) + EPS_CHOL;
    float d22 = D_LONG * uz * uz + D_TRANS * (1.0f - uz * uz) + EPS_CHOL;
    float d10 = (D_LONG - D_TRANS) * uy * ux;
    float d20 = (D_LONG - D_TRANS) * uz * ux;
    float d21 = (D_LONG - D_TRANS) * uz * uy;

    float L00 = sqrtf(d00);
    float L10 = d10 / L00;
    float L20 = d20 / L00;
    float L11 = sqrtf(d11 - L10 * L10);
    float L21 = (d21 - L20 * L10) / L11;
    float L22 = sqrtf(d22 - L20 * L20 - L21 * L21);

    // ---- write 12 floats as 3x float4 (48B stride, 16B aligned) ----
    float4* o = (float4*)(out + (size_t)p * 12);
    o[0] = make_float4(dr0, dr1, dr2, L00);
    o[1] = make_float4(0.0f, 0.0f, L10, L11);
    o[2] = make_float4(0.0f, L20, L21, L22);
}

extern "C" void kernel_launch(void* const* d_in, const int* in_sizes, int n_in,
                              void* d_out, int out_size, void* d_ws, size_t ws_size,
                              hipStream_t stream) {
    const float* pot = (const float*)d_in[0];   // potential_field (256^3)
    const float* vec = (const float*)d_in[1];   // vector_field (256^3 x 3)
    const float* aff = (const float*)d_in[2];   // affine 4x4
    const float* pos = (const float*)d_in[3];   // positions (N,3)
    float* out = (float*)d_out;

    int n = in_sizes[3] / 3;

    sde_kernel<<<(n + 255) / 256, 256, 0, stream>>>(pot, vec, aff, pos, out, n);
}